// Round 9
// baseline (180.274 us; speedup 1.0000x reference)
//
#include <hip/hip_runtime.h>
#include <hip/hip_bf16.h>

#define DEVI __device__ __forceinline__

typedef __attribute__((ext_vector_type(8))) short short8;
typedef __attribute__((ext_vector_type(4))) unsigned short ushort4v;
typedef __attribute__((ext_vector_type(4))) float f32x4;

static constexpr int TT = 64, KIN = 4894, E = 128;
static constexpr float L2E = 1.4426950408889634f;

DEVI unsigned short f2bf(float f) {
    union { float f; unsigned u; } v; v.f = f;
    unsigned r = v.u + 0x7fffu + ((v.u >> 16) & 1u);
    return (unsigned short)(r >> 16);
}
// args pre-scaled by log2(e): exp(x) == exp2(x*L2E)
DEVI float sigm2(float x) { return __builtin_amdgcn_rcpf(1.f + __builtin_amdgcn_exp2f(-x)); }
DEVI float tanh2(float x) { return 1.f - 2.f * __builtin_amdgcn_rcpf(__builtin_amdgcn_exp2f(x + x) + 1.f); }

// LDS-only barrier: ds ops drained, global loads stay in flight (no vmcnt(0) drain).
DEVI void bar_lds() {
    asm volatile("s_waitcnt lgkmcnt(0)" ::: "memory");
    __builtin_amdgcn_s_barrier();
}

// f32 -> bf16*scale fragment loaders (in-register weight conversion; no staging pass)
DEVI short8 cvt8(const float* __restrict__ p, float s) { // 8B-aligned rows
    float2 v0 = *(const float2*)p, v1 = *(const float2*)(p + 2);
    float2 v2 = *(const float2*)(p + 4), v3 = *(const float2*)(p + 6);
    short8 r;
    r[0] = (short)f2bf(v0.x * s); r[1] = (short)f2bf(v0.y * s);
    r[2] = (short)f2bf(v1.x * s); r[3] = (short)f2bf(v1.y * s);
    r[4] = (short)f2bf(v2.x * s); r[5] = (short)f2bf(v2.y * s);
    r[6] = (short)f2bf(v3.x * s); r[7] = (short)f2bf(v3.y * s);
    return r;
}
DEVI short8 cvt8s(const float* __restrict__ p, float s) { // 4B-aligned (scalar loads)
    short8 r;
    #pragma unroll
    for (int jj = 0; jj < 8; ++jj) r[jj] = (short)f2bf(p[jj] * s);
    return r;
}

// ---------------- emb partials: K-split GEMM, 512 blocks = (m-tile 0..127) x (ksplit 0..3) ----------------
__global__ __launch_bounds__(256) void emb_gemm(const float* __restrict__ x,
                                                const float* __restrict__ Wemb,
                                                float* __restrict__ pout) {
    const int ks = blockIdx.x & 3, m0 = (blockIdx.x >> 2) * 16;
    const int w = threadIdx.x >> 6, l = threadIdx.x & 63, lr = l & 15, lo = l >> 4;
    const int n0 = (2 * w) * 16 + lr, n1 = (2 * w + 1) * 16 + lr;
    const float* xrow = x + (long)(m0 + lr) * KIN;
    const float* w0 = Wemb + (long)n0 * KIN;
    const float* w1 = Wemb + (long)n1 * KIN;
    const int k0 = ks * 1216;
    f32x4 acc0 = {0, 0, 0, 0}, acc1 = {0, 0, 0, 0};
    #pragma unroll 2
    for (int kt = 0; kt < 38; ++kt) {
        int k = k0 + kt * 32 + lo * 8;
        short8 a  = cvt8(xrow + k, 1.f);
        short8 b0 = cvt8(w0 + k, 1.f);
        short8 b1 = cvt8(w1 + k, 1.f);
        acc0 = __builtin_amdgcn_mfma_f32_16x16x32_bf16(a, b0, acc0, 0, 0, 0);
        acc1 = __builtin_amdgcn_mfma_f32_16x16x32_bf16(a, b1, acc1, 0, 0, 0);
    }
    if (ks == 3) { // tail k-tile at 4864: guard columns >= 4894
        int k = 4864 + lo * 8;
        short8 a, b0, b1;
        #pragma unroll
        for (int jj = 0; jj < 8; ++jj) {
            int c = k + jj;
            bool ok = (c < KIN);
            a[jj]  = ok ? (short)f2bf(xrow[c]) : (short)0;
            b0[jj] = ok ? (short)f2bf(w0[c]) : (short)0;
            b1[jj] = ok ? (short)f2bf(w1[c]) : (short)0;
        }
        acc0 = __builtin_amdgcn_mfma_f32_16x16x32_bf16(a, b0, acc0, 0, 0, 0);
        acc1 = __builtin_amdgcn_mfma_f32_16x16x32_bf16(a, b1, acc1, 0, 0, 0);
    }
    float* pbase = pout + (long)ks * 2048 * E;
    #pragma unroll
    for (int r = 0; r < 4; ++r) {
        int m = m0 + lo * 4 + r;
        pbase[(long)m * E + n0] = acc0[r];
        pbase[(long)m * E + n1] = acc1[r];
    }
}

// ---------------- emb_reduce: sum 4 k-split partials -> emb f32 + embbf ----------------
__global__ __launch_bounds__(256) void emb_reduce(const float* __restrict__ pout,
                                                  float* __restrict__ emb, unsigned short* __restrict__ embbf) {
    const long idx = (long)blockIdx.x * 256 + threadIdx.x;
    const long base = idx * 4;
    f32x4 s = *(const f32x4*)(pout + base);
    #pragma unroll
    for (int ks = 1; ks < 4; ++ks) {
        f32x4 v = *(const f32x4*)(pout + (long)ks * 2048 * E + base);
        s[0] += v[0]; s[1] += v[1]; s[2] += v[2]; s[3] += v[3];
    }
    *(f32x4*)(emb + base) = s;
    ushort4v h;
    #pragma unroll
    for (int jj = 0; jj < 4; ++jj) h[jj] = f2bf(s[jj]);
    *(ushort4v*)(embbf + base) = h;
}

// ---------------- Gi3 = log2e*(temb @ Wih^T + bih + bhh(r,z)), [tok][gru][u][r,z,n,pad] ----------------
__global__ __launch_bounds__(256) void gi_gemm(const unsigned short* __restrict__ embbf,
                                               const float* __restrict__ Wih_a, const float* __restrict__ Wih_b,
                                               const float* __restrict__ t,
                                               const float* __restrict__ bih_a, const float* __restrict__ bih_b,
                                               const float* __restrict__ bhh_a, const float* __restrict__ bhh_b,
                                               float* __restrict__ Gi3) {
    const int m0 = blockIdx.x * 16;
    const int w = threadIdx.x >> 6, l = threadIdx.x & 63, lr = l & 15, lo = l >> 4;
    f32x4 acc[12];
    #pragma unroll
    for (int nl = 0; nl < 12; ++nl) acc[nl] = (f32x4){0, 0, 0, 0};
    #pragma unroll
    for (int kt = 0; kt < 4; ++kt) {
        int k = kt * 32 + lo * 8;
        short8 a0 = *(const short8*)(embbf + (long)(m0 + lr) * E + k);
        #pragma unroll
        for (int nl = 0; nl < 12; ++nl) {
            int n = (w * 12 + nl) * 16 + lr;
            const float* src = ((n < 384) ? (Wih_a + (long)n * 129) : (Wih_b + (long)(n - 384) * 129)) + k;
            short8 bf = cvt8s(src, L2E);
            acc[nl] = __builtin_amdgcn_mfma_f32_16x16x32_bf16(a0, bf, acc[nl], 0, 0, 0);
        }
    }
    #pragma unroll
    for (int nl = 0; nl < 12; ++nl) {
        int n = (w * 12 + nl) * 16 + lr;
        int gru = (n >= 384) ? 1 : 0;
        int nn = n - gru * 384;
        int gt = nn >> 7, u = nn & 127;
        float bias = (gru ? bih_b[nn] : bih_a[nn]);
        if (gt < 2) bias += (gru ? bhh_b[nn] : bhh_a[nn]);
        float cw = (n < 384) ? Wih_a[(long)n * 129 + 128] : Wih_b[(long)(n - 384) * 129 + 128];
        #pragma unroll
        for (int r = 0; r < 4; ++r) {
            int tok = m0 + lo * 4 + r;
            Gi3[((long)(tok * 2 + gru) * 128 + u) * 4 + gt] = acc[nl][r] + (bias + t[tok] * cw) * L2E;
        }
    }
}

// ---------------- recurrence, ONE GRU per block ----------------
// 256 blocks = (i 0..63) x (q 0..1) x (g 0..1). 512 thr, 8 waves; wave w owns u-slice w*16+lr.
// Round-9: (1) lgkmcnt-only barrier -> prefetch loads stay in flight across iterations;
// (2) alpha score via broadcast-w_alpha MFMA (every output column = score) -> no shfl/red
//     path for alpha, 4 lanes write p=exp2(s) directly to pd_s (lag 1);
// (3) pointer-decrement prefetch addressing; v_cvt_pk_bf16_f32 for H->bf16 stores;
// (4) all weights converted f32->bf16*log2e in-register (prep kernel removed).
__global__ __launch_bounds__(512) __attribute__((amdgpu_waves_per_eu(2, 2)))
void retain_rec(const float* __restrict__ Whh_a, const float* __restrict__ Whh_b,
                const float* __restrict__ Wbeta,
                const float* __restrict__ Gi3, const float* __restrict__ emb,
                const float* __restrict__ bhh_a, const float* __restrict__ bhh_b,
                const float* __restrict__ w_alpha, const float* __restrict__ b_alpha,
                const float* __restrict__ b_beta, const float* __restrict__ Wout,
                float* __restrict__ p_g, float* __restrict__ d_g) {
    const int tid = threadIdx.x;
    const int w = tid >> 6, l = tid & 63, lr = l & 15, lo = l >> 4;
    const int i = blockIdx.x >> 2, q = (blockIdx.x >> 1) & 1, g = blockIdx.x & 1;
    const int u = w * 16 + lr;

    __shared__ __align__(16) unsigned short Hbf[2][16][128]; // [buf][c][u ^ ((c&7)*8)]
    __shared__ float red[2][8][16];                          // beta partial sums (parity-lagged)
    __shared__ float pd_s[16][66];                           // per-step p (alpha) / d (beta)

    for (int idx = tid; idx < 2 * 16 * 128; idx += 512) (&Hbf[0][0][0])[idx] = 0; // H_{-1}=0

    // Whh B-fragments (rows are 512B-aligned -> float2-based cvt8)
    const float* WhhG = g ? Whh_b : Whh_a;
    short8 Wf[3][4];
    #pragma unroll
    for (int gt = 0; gt < 3; ++gt)
        #pragma unroll
        for (int kt = 0; kt < 4; ++kt)
            Wf[gt][kt] = cvt8(WhhG + (long)(gt * 128 + u) * 128 + kt * 32 + lo * 8, L2E);

    // Xf: beta -> Wbeta row u; alpha -> w_alpha broadcast into EVERY B row (all cols = score)
    short8 Xf[4];
    #pragma unroll
    for (int kt = 0; kt < 4; ++kt)
        Xf[kt] = g ? cvt8(Wbeta + (long)u * 128 + kt * 32 + lo * 8, L2E)
                   : cvt8(w_alpha + kt * 32 + lo * 8, L2E);

    const float bhnL = (g ? bhh_b : bhh_a)[256 + u] * L2E;
    const float bbetL = g ? b_beta[u] * L2E : 0.f;
    const float wo = g ? Wout[u] : 0.f;
    const float balL = b_alpha[0] * L2E;

    float h_old[4] = {0, 0, 0, 0};

    // prefetch pointers: token index decreases by 1 per iteration
    const f32x4* gp[4];
    const float* ep[4];
    #pragma unroll
    for (int r = 0; r < 4; ++r) {
        int tok = (q * 16 + lo * 4 + r) * 64 + i;
        gp[r] = (const f32x4*)Gi3 + ((long)(tok * 2 + g) * 128 + u);
        ep[r] = emb + (long)tok * E + u;
    }
    f32x4 giv[4];
    #pragma unroll
    for (int r = 0; r < 4; ++r) giv[r] = *gp[r]; // token i, consumed at n=0
    float ev[4] = {0, 0, 0, 0};

    __syncthreads();

    const int iend = i + 1 + g; // alpha's last p-write at n=i+1; beta's last d-write at n=i+2
    for (int n = 0; n <= iend; ++n) {
        const int rb = n & 1, wb = rb ^ 1;
        const bool do_gate = (n <= i);
        const bool do_post = (n >= 1) && (n <= i + 1);
        const bool ld_gi = (n < i);
        const bool ld_ev = g && (n <= i);

        // ---- issue next-iteration global loads (in flight across the lgkm-only barrier) ----
        f32x4 givn[4];
        float evn[4];
        if (ld_gi) {
            #pragma unroll
            for (int r = 0; r < 4; ++r) { gp[r] -= 256; givn[r] = *gp[r]; } // token i-n-1
        }
        if (ld_ev) {
            #pragma unroll
            for (int r = 0; r < 4; ++r) { evn[r] = *ep[r]; ep[r] -= E; }    // token i-n
        }

        // ---- beta wave0: finish d for step n-2 from red[wb] ----
        if (g && w == 0 && l < 16 && n >= 2) {
            float d = 0.f;
            #pragma unroll
            for (int ww = 0; ww < 8; ++ww) d += red[wb][ww][l];
            pd_s[l][n - 2] = d;
        }

        // ---- A-fragments from swizzled LDS (H_{n-1}) ----
        short8 Af[4];
        if (do_gate || do_post) {
            #pragma unroll
            for (int kt = 0; kt < 4; ++kt) {
                int sw = (kt * 32 + lo * 8) ^ ((lr & 7) * 8);
                Af[kt] = *(const short8*)(&Hbf[rb][lr][sw]);
            }
        }

        // ---- MFMA: 3 gate tiles ----
        f32x4 gh0 = {0, 0, 0, 0}, gh1 = {0, 0, 0, 0}, gh2 = {bhnL, bhnL, bhnL, bhnL};
        if (do_gate) {
            #pragma unroll
            for (int kt = 0; kt < 4; ++kt) {
                gh0 = __builtin_amdgcn_mfma_f32_16x16x32_bf16(Af[kt], Wf[0][kt], gh0, 0, 0, 0);
                gh1 = __builtin_amdgcn_mfma_f32_16x16x32_bf16(Af[kt], Wf[1][kt], gh1, 0, 0, 0);
                gh2 = __builtin_amdgcn_mfma_f32_16x16x32_bf16(Af[kt], Wf[2][kt], gh2, 0, 0, 0);
            }
        }

        // ---- MFMA: score (alpha) / beta-preact (beta) of H_{n-1} ----
        if (do_post) {
            f32x4 xacc = {0, 0, 0, 0};
            #pragma unroll
            for (int kt = 0; kt < 4; ++kt)
                xacc = __builtin_amdgcn_mfma_f32_16x16x32_bf16(Af[kt], Xf[kt], xacc, 0, 0, 0);
            if (!g) {
                // every column holds the score; lanes (w==0, lr==0) cover all 16 chains
                if (w == 0 && lr == 0) {
                    #pragma unroll
                    for (int r = 0; r < 4; ++r)
                        pd_s[lo * 4 + r][n - 1] = __builtin_amdgcn_exp2f(xacc[r] + balL);
                }
            } else {
                float dp[4];
                #pragma unroll
                for (int r = 0; r < 4; ++r) dp[r] = tanh2(xacc[r] + bbetL) * ev[r] * wo;
                #pragma unroll
                for (int r = 0; r < 4; ++r) {
                    dp[r] += __shfl_xor(dp[r], 1);
                    dp[r] += __shfl_xor(dp[r], 2);
                    dp[r] += __shfl_xor(dp[r], 4);
                    dp[r] += __shfl_xor(dp[r], 8);
                }
                if (lr == 0) {
                    #pragma unroll
                    for (int r = 0; r < 4; ++r) red[rb][w][lo * 4 + r] = dp[r];
                }
            }
        }

        // ---- gates: H_n = GRU(H_{n-1}, x_{i-n}) ----
        if (do_gate) {
            float hn[4];
            #pragma unroll
            for (int r = 0; r < 4; ++r) {
                f32x4 gv = giv[r];
                float rr = sigm2(gv[0] + gh0[r]);
                float zz = sigm2(gv[1] + gh1[r]);
                float nnv = tanh2(gv[2] + rr * gh2[r]);
                float h = nnv + zz * (h_old[r] - nnv);
                h_old[r] = h;
                hn[r] = h;
            }
            unsigned pk01, pk23;
            asm("v_cvt_pk_bf16_f32 %0, %1, %2" : "=v"(pk01) : "v"(hn[0]), "v"(hn[1]));
            asm("v_cvt_pk_bf16_f32 %0, %1, %2" : "=v"(pk23) : "v"(hn[2]), "v"(hn[3]));
            const int c0 = lo * 4;
            Hbf[wb][c0 + 0][u ^ (((c0 + 0) & 7) * 8)] = (unsigned short)pk01;
            Hbf[wb][c0 + 1][u ^ (((c0 + 1) & 7) * 8)] = (unsigned short)(pk01 >> 16);
            Hbf[wb][c0 + 2][u ^ (((c0 + 2) & 7) * 8)] = (unsigned short)pk23;
            Hbf[wb][c0 + 3][u ^ (((c0 + 3) & 7) * 8)] = (unsigned short)(pk23 >> 16);
        }

        // ---- rotate prefetch buffers ----
        if (ld_gi) {
            #pragma unroll
            for (int r = 0; r < 4; ++r) giv[r] = givn[r];
        }
        if (ld_ev) {
            #pragma unroll
            for (int r = 0; r < 4; ++r) ev[r] = evn[r];
        }

        bar_lds();
    }

    // ---- bulk dump p/d (steps 0..i) ----
    float* dst = g ? d_g : p_g;
    for (int idx = tid; idx < 16 * 64; idx += 512) {
        int c = idx >> 6, kk = idx & 63;
        if (kk <= i) {
            long row = (long)(q * 16 + c) * 64 + i;
            dst[row * 64 + kk] = pd_s[c][kk];
        }
    }
}

// ---------------- reduce: out[b,i] = sum_k p*d / sum_k p + b_out ----------------
__global__ __launch_bounds__(512) void reduce_out(const float* __restrict__ p_g, const float* __restrict__ d_g,
                                                  const int* __restrict__ lengths, const float* __restrict__ b_out,
                                                  float* __restrict__ out) {
    const int w = threadIdx.x >> 6, l = threadIdx.x & 63;
    const int row = blockIdx.x * 8 + w; // b*64 + i
    const int b = row >> 6, i = row & 63;
    float p = (l <= i) ? p_g[(long)row * 64 + l] : 0.f;
    float d = (l <= i) ? d_g[(long)row * 64 + l] : 0.f;
    float pd = p * d;
    #pragma unroll
    for (int off = 1; off < 64; off <<= 1) {
        p += __shfl_xor(p, off);
        pd += __shfl_xor(pd, off);
    }
    if (l == 0) {
        float val = (i < lengths[b]) ? pd / p + b_out[0] : b_out[0];
        out[row] = val;
    }
}

// ---------------- launch ----------------
extern "C" void kernel_launch(void* const* d_in, const int* in_sizes, int n_in,
                              void* d_out, int out_size, void* d_ws, size_t ws_size,
                              hipStream_t stream) {
    (void)in_sizes; (void)n_in; (void)out_size; (void)ws_size;
    const float* x       = (const float*)d_in[0];
    const float* t       = (const float*)d_in[1];
    const int*   len     = (const int*)d_in[2];
    const float* Wemb    = (const float*)d_in[3];
    const float* Wih_a   = (const float*)d_in[4];
    const float* Whh_a   = (const float*)d_in[5];
    const float* bih_a   = (const float*)d_in[6];
    const float* bhh_a   = (const float*)d_in[7];
    const float* Wih_b   = (const float*)d_in[8];
    const float* Whh_b   = (const float*)d_in[9];
    const float* bih_b   = (const float*)d_in[10];
    const float* bhh_b   = (const float*)d_in[11];
    const float* w_alpha = (const float*)d_in[12];
    const float* b_alpha = (const float*)d_in[13];
    const float* W_beta  = (const float*)d_in[14];
    const float* b_beta  = (const float*)d_in[15];
    const float* W_out   = (const float*)d_in[16];
    const float* b_out   = (const float*)d_in[17];

    char* ws = (char*)d_ws;
    float*          emb   = (float*)(ws + 0);                 // 2048*128*4     = 1,048,576
    unsigned short* embbf = (unsigned short*)(ws + 1048576);  // 2048*128*2     =   524,288
    float*          Gi3   = (float*)(ws + 1572864);           // 2048*2*128*4*4 = 8,388,608
    float*          p_g   = (float*)(ws + 9961472);           // 2048*64*4      =   524,288
    float*          d_g   = (float*)(ws + 10485760);          // 2048*64*4      =   524,288
    float*          pout  = (float*)(ws + 11010048);          // 4*2048*128*4   = 4,194,304

    emb_gemm<<<512, 256, 0, stream>>>(x, Wemb, pout);
    emb_reduce<<<256, 256, 0, stream>>>(pout, emb, embbf);
    gi_gemm<<<128, 256, 0, stream>>>(embbf, Wih_a, Wih_b, t, bih_a, bih_b, bhh_a, bhh_b, Gi3);
    retain_rec<<<256, 512, 0, stream>>>(Whh_a, Whh_b, W_beta, Gi3, emb, bhh_a, bhh_b,
                                        w_alpha, b_alpha, b_beta, W_out, p_g, d_g);
    reduce_out<<<256, 512, 0, stream>>>(p_g, d_g, len, b_out, (float*)d_out);
}

// Round 10
// 164.522 us; speedup vs baseline: 1.0957x; 1.0957x over previous
//
#include <hip/hip_runtime.h>
#include <hip/hip_bf16.h>

#define DEVI __device__ __forceinline__

typedef __attribute__((ext_vector_type(8))) short short8;
typedef __attribute__((ext_vector_type(8))) unsigned short ushort8;
typedef __attribute__((ext_vector_type(4))) unsigned short ushort4v;
typedef __attribute__((ext_vector_type(2))) unsigned int u32x2;
typedef __attribute__((ext_vector_type(4))) float f32x4;

static constexpr int TT = 64, KIN = 4894, KINP = 4896, E = 128;
static constexpr float L2E = 1.4426950408889634f;

DEVI unsigned short f2bf(float f) {
    union { float f; unsigned u; } v; v.f = f;
    unsigned r = v.u + 0x7fffu + ((v.u >> 16) & 1u);
    return (unsigned short)(r >> 16);
}
// args pre-scaled by log2(e): exp(x) == exp2(x*L2E)
DEVI float sigm2(float x) { return __builtin_amdgcn_rcpf(1.f + __builtin_amdgcn_exp2f(-x)); }
DEVI float tanh2(float x) { return 1.f - 2.f * __builtin_amdgcn_rcpf(__builtin_amdgcn_exp2f(x + x) + 1.f); }

// LDS-only barrier: ds ops drained, global loads stay in flight.
DEVI void bar_lds() {
    asm volatile("s_waitcnt lgkmcnt(0)" ::: "memory");
    __builtin_amdgcn_s_barrier();
}

DEVI short8 cvt8(const float* __restrict__ p, float s) {
    float2 v0 = *(const float2*)p, v1 = *(const float2*)(p + 2);
    float2 v2 = *(const float2*)(p + 4), v3 = *(const float2*)(p + 6);
    short8 r;
    r[0] = (short)f2bf(v0.x * s); r[1] = (short)f2bf(v0.y * s);
    r[2] = (short)f2bf(v1.x * s); r[3] = (short)f2bf(v1.y * s);
    r[4] = (short)f2bf(v2.x * s); r[5] = (short)f2bf(v2.y * s);
    r[6] = (short)f2bf(v3.x * s); r[7] = (short)f2bf(v3.y * s);
    return r;
}

// ---------------- prep: weight casts (Wih/Whh/Wbeta pre-scaled by log2e) ----------------
__global__ void prep_kernel(const float* __restrict__ Wemb,
                            const float* __restrict__ Wih_a, const float* __restrict__ Wih_b,
                            const float* __restrict__ Whh_a, const float* __restrict__ Whh_b,
                            const float* __restrict__ Wbeta,
                            unsigned short* __restrict__ wembbf, unsigned short* __restrict__ wihbf,
                            unsigned short* __restrict__ whhbf, unsigned short* __restrict__ wbetabf) {
    int job = blockIdx.x * blockDim.x + threadIdx.x;
    const int JWE = 128 * 612, JWIH = 768 * 16, JWHH = 768 * 16, JWB = 128 * 16;
    if (job < JWE) {
        int row = job / 612, c8 = (job % 612) * 8;
        ushort8 v;
        #pragma unroll
        for (int jj = 0; jj < 8; ++jj) { int c = c8 + jj; v[jj] = (c < KIN) ? f2bf(Wemb[(long)row * KIN + c]) : (unsigned short)0; }
        *(ushort8*)(wembbf + (long)row * KINP + c8) = v;
        return;
    }
    job -= JWE;
    if (job < JWIH) {
        int g = job / 16, c8 = (job % 16) * 8;
        const float* src = (g < 384) ? (Wih_a + (long)g * 129) : (Wih_b + (long)(g - 384) * 129);
        ushort8 v;
        #pragma unroll
        for (int jj = 0; jj < 8; ++jj) v[jj] = f2bf(src[c8 + jj] * L2E);
        *(ushort8*)(wihbf + (long)g * 128 + c8) = v;
        return;
    }
    job -= JWIH;
    if (job < JWHH) {
        int g = job / 16, c8 = (job % 16) * 8;
        const float* src = (g < 384) ? (Whh_a + (long)g * 128) : (Whh_b + (long)(g - 384) * 128);
        ushort8 v;
        #pragma unroll
        for (int jj = 0; jj < 8; ++jj) v[jj] = f2bf(src[c8 + jj] * L2E);
        *(ushort8*)(whhbf + (long)g * 128 + c8) = v;
        return;
    }
    job -= JWHH;
    if (job < JWB) {
        int e = job / 16, c8 = (job % 16) * 8;
        ushort8 v;
        #pragma unroll
        for (int jj = 0; jj < 8; ++jj) v[jj] = f2bf(Wbeta[(long)e * 128 + c8 + jj] * L2E);
        *(ushort8*)(wbetabf + (long)e * 128 + c8) = v;
    }
}

// ---------------- emb partials: K-split GEMM, 512 blocks = (m-tile 0..127) x (ksplit 0..3) ----------------
__global__ __launch_bounds__(256) void emb_gemm(const float* __restrict__ x,
                                                const unsigned short* __restrict__ wembbf,
                                                float* __restrict__ pout) {
    const int ks = blockIdx.x & 3, m0 = (blockIdx.x >> 2) * 16;
    const int w = threadIdx.x >> 6, l = threadIdx.x & 63, lr = l & 15, lo = l >> 4;
    const int n0 = (2 * w) * 16 + lr, n1 = (2 * w + 1) * 16 + lr;
    const float* xrow = x + (long)(m0 + lr) * KIN;
    const int k0 = ks * 1216;
    f32x4 acc0 = {0, 0, 0, 0}, acc1 = {0, 0, 0, 0};
    #pragma unroll 2
    for (int kt = 0; kt < 38; ++kt) {
        int k = k0 + kt * 32 + lo * 8;
        short8 a = cvt8(xrow + k, 1.f);
        short8 b0 = *(const short8*)(wembbf + (long)n0 * KINP + k);
        short8 b1 = *(const short8*)(wembbf + (long)n1 * KINP + k);
        acc0 = __builtin_amdgcn_mfma_f32_16x16x32_bf16(a, b0, acc0, 0, 0, 0);
        acc1 = __builtin_amdgcn_mfma_f32_16x16x32_bf16(a, b1, acc1, 0, 0, 0);
    }
    if (ks == 3) {
        int k = 4864 + lo * 8;
        short8 a;
        #pragma unroll
        for (int jj = 0; jj < 8; ++jj) { int c = k + jj; a[jj] = (c < KIN) ? (short)f2bf(xrow[c]) : (short)0; }
        short8 b0 = *(const short8*)(wembbf + (long)n0 * KINP + k);
        short8 b1 = *(const short8*)(wembbf + (long)n1 * KINP + k);
        acc0 = __builtin_amdgcn_mfma_f32_16x16x32_bf16(a, b0, acc0, 0, 0, 0);
        acc1 = __builtin_amdgcn_mfma_f32_16x16x32_bf16(a, b1, acc1, 0, 0, 0);
    }
    float* pbase = pout + (long)ks * 2048 * E;
    #pragma unroll
    for (int r = 0; r < 4; ++r) {
        int m = m0 + lo * 4 + r;
        pbase[(long)m * E + n0] = acc0[r];
        pbase[(long)m * E + n1] = acc1[r];
    }
}

// ---------------- emb_reduce: sum 4 k-split partials -> emb f32 + embbf ----------------
__global__ __launch_bounds__(256) void emb_reduce(const float* __restrict__ pout,
                                                  float* __restrict__ emb, unsigned short* __restrict__ embbf) {
    const long idx = (long)blockIdx.x * 256 + threadIdx.x;
    const long base = idx * 4;
    f32x4 s = *(const f32x4*)(pout + base);
    #pragma unroll
    for (int ks = 1; ks < 4; ++ks) {
        f32x4 v = *(const f32x4*)(pout + (long)ks * 2048 * E + base);
        s[0] += v[0]; s[1] += v[1]; s[2] += v[2]; s[3] += v[3];
    }
    *(f32x4*)(emb + base) = s;
    ushort4v h;
    #pragma unroll
    for (int jj = 0; jj < 4; ++jj) h[jj] = f2bf(s[jj]);
    *(ushort4v*)(embbf + base) = h;
}

// ---------------- Gi3 = log2e*(temb @ Wih^T + bih + bhh(r,z)), [tok][gru][u][r,z,n,pad] ----------------
__global__ __launch_bounds__(256) void gi_gemm(const unsigned short* __restrict__ embbf,
                                               const unsigned short* __restrict__ wihbf,
                                               const float* __restrict__ Wih_a, const float* __restrict__ Wih_b,
                                               const float* __restrict__ t,
                                               const float* __restrict__ bih_a, const float* __restrict__ bih_b,
                                               const float* __restrict__ bhh_a, const float* __restrict__ bhh_b,
                                               float* __restrict__ Gi3) {
    const int m0 = blockIdx.x * 16;
    const int w = threadIdx.x >> 6, l = threadIdx.x & 63, lr = l & 15, lo = l >> 4;
    f32x4 acc[12];
    #pragma unroll
    for (int nl = 0; nl < 12; ++nl) acc[nl] = (f32x4){0, 0, 0, 0};
    #pragma unroll
    for (int kt = 0; kt < 4; ++kt) {
        int k = kt * 32 + lo * 8;
        short8 a0 = *(const short8*)(embbf + (long)(m0 + lr) * E + k);
        #pragma unroll
        for (int nl = 0; nl < 12; ++nl) {
            int n = (w * 12 + nl) * 16 + lr;
            short8 bf = *(const short8*)(wihbf + (long)n * 128 + k);
            acc[nl] = __builtin_amdgcn_mfma_f32_16x16x32_bf16(a0, bf, acc[nl], 0, 0, 0);
        }
    }
    #pragma unroll
    for (int nl = 0; nl < 12; ++nl) {
        int n = (w * 12 + nl) * 16 + lr;
        int gru = (n >= 384) ? 1 : 0;
        int nn = n - gru * 384;
        int gt = nn >> 7, u = nn & 127;
        float bias = (gru ? bih_b[nn] : bih_a[nn]);
        if (gt < 2) bias += (gru ? bhh_b[nn] : bhh_a[nn]);
        float cw = (n < 384) ? Wih_a[(long)n * 129 + 128] : Wih_b[(long)(n - 384) * 129 + 128];
        #pragma unroll
        for (int r = 0; r < 4; ++r) {
            int tok = m0 + lo * 4 + r;
            Gi3[((long)(tok * 2 + gru) * 128 + u) * 4 + gt] = acc[nl][r] + (bias + t[tok] * cw) * L2E;
        }
    }
}

// ---------------- recurrence, ONE GRU per block ----------------
// 256 blocks = (i 0..63) x (q 0..1) x (g 0..1). 512 thr, 8 waves.
// Round-10: MFMA operands SWAPPED (A = weights, B = H) -> D[row=u][col=chain]:
// each thread owns (chain c = lr, features u0..u0+3 consecutive). H/M LDS stores are ONE
// packed ds_write_b64 (2x v_cvt_pk_bf16_f32). Beta's e-reduction is a ones-MFMA over an
// LDS-staged M = tanh(.)·ev·wo tile (parity double-buffered) -> the 128-shfl/iter chain
// and red[] round-trips are gone. Alpha score stays broadcast-MFMA.
__global__ __launch_bounds__(512) __attribute__((amdgpu_waves_per_eu(2, 2)))
void retain_rec(const unsigned short* __restrict__ whhbf, const unsigned short* __restrict__ wbetabf,
                const float* __restrict__ Gi3, const float* __restrict__ emb,
                const float* __restrict__ bhh_a, const float* __restrict__ bhh_b,
                const float* __restrict__ w_alpha, const float* __restrict__ b_alpha,
                const float* __restrict__ b_beta, const float* __restrict__ Wout,
                float* __restrict__ p_g, float* __restrict__ d_g) {
    const int tid = threadIdx.x;
    const int w = tid >> 6, l = tid & 63, lr = l & 15, lo = l >> 4;
    const int i = blockIdx.x >> 2, q = (blockIdx.x >> 1) & 1, g = blockIdx.x & 1;
    const int u0 = w * 16 + lo * 4; // this thread's 4 features; chain = lr

    __shared__ __align__(16) unsigned short Hbf[2][16][128]; // [buf][c][u ^ ((c&7)*8)]
    __shared__ __align__(16) unsigned short Mld[2][16][128]; // beta: M = tanh·ev·wo, bf16
    __shared__ float pd_s[16][66];

    for (int idx = tid; idx < 2 * 16 * 128; idx += 512) (&Hbf[0][0][0])[idx] = 0; // H_{-1}=0

    // A-operand weight fragments (A-row = feature index)
    short8 Wf[3][4];
    #pragma unroll
    for (int gt = 0; gt < 3; ++gt)
        #pragma unroll
        for (int kt = 0; kt < 4; ++kt)
            Wf[gt][kt] = *(const short8*)(whhbf + (long)(g * 384 + gt * 128 + w * 16 + lr) * 128 + kt * 32 + lo * 8);
    short8 Xf[4]; // beta: Wbeta e-rows; alpha: w_alpha broadcast into every A row
    #pragma unroll
    for (int kt = 0; kt < 4; ++kt)
        Xf[kt] = g ? *(const short8*)(wbetabf + (long)(w * 16 + lr) * 128 + kt * 32 + lo * 8)
                   : cvt8(w_alpha + kt * 32 + lo * 8, L2E);
    short8 ones;
    #pragma unroll
    for (int jj = 0; jj < 8; ++jj) ones[jj] = (short)0x3F80; // bf16 1.0

    const float* bhhG = g ? bhh_b : bhh_a;
    f32x4 bhn4 = *(const f32x4*)(bhhG + 256 + u0);
    #pragma unroll
    for (int r = 0; r < 4; ++r) bhn4[r] *= L2E;
    f32x4 bb4 = {0, 0, 0, 0}, wo4 = {0, 0, 0, 0};
    if (g) {
        bb4 = *(const f32x4*)(b_beta + u0);
        #pragma unroll
        for (int r = 0; r < 4; ++r) bb4[r] *= L2E;
        wo4 = *(const f32x4*)(Wout + u0);
    }
    const float balL = b_alpha[0] * L2E;

    float h_old[4] = {0, 0, 0, 0};

    // prefetch pointers (token decreases by 1 per iteration); chain = lr
    const int tok0 = (q * 16 + lr) * 64 + i;
    const f32x4* gp = (const f32x4*)Gi3 + ((long)(tok0 * 2 + g) * 128 + u0);
    const float* ep = emb + (long)tok0 * E + u0;
    f32x4 giv[4];
    #pragma unroll
    for (int r = 0; r < 4; ++r) giv[r] = gp[r]; // token i, consumed at n=0
    f32x4 ev = {0, 0, 0, 0};

    __syncthreads();

    const int iend = i + 1 + g;
    for (int n = 0; n <= iend; ++n) {
        const int rb = n & 1, wb = rb ^ 1;
        const bool do_gate = (n <= i);
        const bool do_post = (n >= 1) && (n <= i + 1);
        const bool ld_gi = (n < i);
        const bool ld_ev = g && (n <= i); // iter m loads token i-m, consumed at m+1 (j2=i-m)

        // ---- issue next-iteration global loads ----
        f32x4 givn[4], evn;
        if (ld_gi) {
            gp -= 256; // one token
            #pragma unroll
            for (int r = 0; r < 4; ++r) givn[r] = gp[r];
        }
        if (ld_ev) { evn = *(const f32x4*)ep; ep -= E; }

        // ---- beta wave0: d for step n-2 = ones-MFMA over Mld[wb] ----
        if (g && w == 0 && n >= 2) {
            f32x4 dacc = {0, 0, 0, 0};
            #pragma unroll
            for (int kt = 0; kt < 4; ++kt) {
                int sw = (kt * 32 + lo * 8) ^ ((lr & 7) * 8);
                short8 bm = *(const short8*)(&Mld[wb][lr][sw]);
                dacc = __builtin_amdgcn_mfma_f32_16x16x32_bf16(ones, bm, dacc, 0, 0, 0);
            }
            if (lo == 0) pd_s[lr][n - 2] = dacc[0];
        }

        // ---- B-operand fragments: H_{n-1} rows = chains ----
        short8 Af[4];
        if (do_gate || do_post) {
            #pragma unroll
            for (int kt = 0; kt < 4; ++kt) {
                int sw = (kt * 32 + lo * 8) ^ ((lr & 7) * 8);
                Af[kt] = *(const short8*)(&Hbf[rb][lr][sw]);
            }
        }

        // ---- MFMA: gates (A=Whh rows=u, B=H rows=c) -> D[u][c] ----
        f32x4 gh0 = {0, 0, 0, 0}, gh1 = {0, 0, 0, 0}, gh2 = bhn4;
        if (do_gate) {
            #pragma unroll
            for (int kt = 0; kt < 4; ++kt) {
                gh0 = __builtin_amdgcn_mfma_f32_16x16x32_bf16(Wf[0][kt], Af[kt], gh0, 0, 0, 0);
                gh1 = __builtin_amdgcn_mfma_f32_16x16x32_bf16(Wf[1][kt], Af[kt], gh1, 0, 0, 0);
                gh2 = __builtin_amdgcn_mfma_f32_16x16x32_bf16(Wf[2][kt], Af[kt], gh2, 0, 0, 0);
            }
        }

        // ---- MFMA: score (alpha) / beta preact of H_{n-1} ----
        if (do_post) {
            f32x4 xacc = {0, 0, 0, 0};
            #pragma unroll
            for (int kt = 0; kt < 4; ++kt)
                xacc = __builtin_amdgcn_mfma_f32_16x16x32_bf16(Xf[kt], Af[kt], xacc, 0, 0, 0);
            if (!g) {
                if (w == 0 && lo == 0) pd_s[lr][n - 1] = __builtin_amdgcn_exp2f(xacc[0] + balL);
            } else {
                float m0v = tanh2(xacc[0] + bb4[0]) * ev[0] * wo4[0];
                float m1v = tanh2(xacc[1] + bb4[1]) * ev[1] * wo4[1];
                float m2v = tanh2(xacc[2] + bb4[2]) * ev[2] * wo4[2];
                float m3v = tanh2(xacc[3] + bb4[3]) * ev[3] * wo4[3];
                unsigned mp0, mp1;
                asm("v_cvt_pk_bf16_f32 %0, %1, %2" : "=v"(mp0) : "v"(m0v), "v"(m1v));
                asm("v_cvt_pk_bf16_f32 %0, %1, %2" : "=v"(mp1) : "v"(m2v), "v"(m3v));
                *(u32x2*)(&Mld[rb][lr][u0 ^ ((lr & 7) * 8)]) = (u32x2){mp0, mp1};
            }
        }

        // ---- gates: H_n = GRU(H_{n-1}, x_{i-n}); packed b64 store ----
        if (do_gate) {
            float hn[4];
            #pragma unroll
            for (int r = 0; r < 4; ++r) {
                f32x4 gv = giv[r];
                float rr = sigm2(gv[0] + gh0[r]);
                float zz = sigm2(gv[1] + gh1[r]);
                float nv = tanh2(gv[2] + rr * gh2[r]);
                float h = nv + zz * (h_old[r] - nv);
                h_old[r] = h;
                hn[r] = h;
            }
            unsigned p0, p1;
            asm("v_cvt_pk_bf16_f32 %0, %1, %2" : "=v"(p0) : "v"(hn[0]), "v"(hn[1]));
            asm("v_cvt_pk_bf16_f32 %0, %1, %2" : "=v"(p1) : "v"(hn[2]), "v"(hn[3]));
            *(u32x2*)(&Hbf[wb][lr][u0 ^ ((lr & 7) * 8)]) = (u32x2){p0, p1};
        }

        // ---- rotate prefetch buffers ----
        if (ld_gi) {
            #pragma unroll
            for (int r = 0; r < 4; ++r) giv[r] = givn[r];
        }
        if (ld_ev) ev = evn;

        bar_lds();
    }

    // ---- bulk dump p/d ----
    float* dst = g ? d_g : p_g;
    for (int idx = tid; idx < 16 * 64; idx += 512) {
        int c = idx >> 6, kk = idx & 63;
        if (kk <= i) {
            long row = (long)(q * 16 + c) * 64 + i;
            dst[row * 64 + kk] = pd_s[c][kk];
        }
    }
}

// ---------------- reduce: out[b,i] = sum_k p*d / sum_k p + b_out ----------------
__global__ __launch_bounds__(512) void reduce_out(const float* __restrict__ p_g, const float* __restrict__ d_g,
                                                  const int* __restrict__ lengths, const float* __restrict__ b_out,
                                                  float* __restrict__ out) {
    const int w = threadIdx.x >> 6, l = threadIdx.x & 63;
    const int row = blockIdx.x * 8 + w; // b*64 + i
    const int b = row >> 6, i = row & 63;
    float p = (l <= i) ? p_g[(long)row * 64 + l] : 0.f;
    float d = (l <= i) ? d_g[(long)row * 64 + l] : 0.f;
    float pd = p * d;
    #pragma unroll
    for (int off = 1; off < 64; off <<= 1) {
        p += __shfl_xor(p, off);
        pd += __shfl_xor(pd, off);
    }
    if (l == 0) {
        float val = (i < lengths[b]) ? pd / p + b_out[0] : b_out[0];
        out[row] = val;
    }
}

// ---------------- launch ----------------
extern "C" void kernel_launch(void* const* d_in, const int* in_sizes, int n_in,
                              void* d_out, int out_size, void* d_ws, size_t ws_size,
                              hipStream_t stream) {
    (void)in_sizes; (void)n_in; (void)out_size; (void)ws_size;
    const float* x       = (const float*)d_in[0];
    const float* t       = (const float*)d_in[1];
    const int*   len     = (const int*)d_in[2];
    const float* Wemb    = (const float*)d_in[3];
    const float* Wih_a   = (const float*)d_in[4];
    const float* Whh_a   = (const float*)d_in[5];
    const float* bih_a   = (const float*)d_in[6];
    const float* bhh_a   = (const float*)d_in[7];
    const float* Wih_b   = (const float*)d_in[8];
    const float* Whh_b   = (const float*)d_in[9];
    const float* bih_b   = (const float*)d_in[10];
    const float* bhh_b   = (const float*)d_in[11];
    const float* w_alpha = (const float*)d_in[12];
    const float* b_alpha = (const float*)d_in[13];
    const float* W_beta  = (const float*)d_in[14];
    const float* b_beta  = (const float*)d_in[15];
    const float* W_out   = (const float*)d_in[16];
    const float* b_out   = (const float*)d_in[17];

    char* ws = (char*)d_ws;
    float*          emb     = (float*)(ws + 0);                 // 1,048,576
    unsigned short* embbf   = (unsigned short*)(ws + 1048576);  //   524,288
    float*          Gi3     = (float*)(ws + 1572864);           // 8,388,608
    unsigned short* wembbf  = (unsigned short*)(ws + 9961472);  // 1,253,376
    unsigned short* wihbf   = (unsigned short*)(ws + 11214848); //   196,608
    unsigned short* whhbf   = (unsigned short*)(ws + 11411456); //   196,608
    unsigned short* wbetabf = (unsigned short*)(ws + 11608064); //    32,768
    float*          p_g     = (float*)(ws + 11640832);          //   524,288
    float*          d_g     = (float*)(ws + 12165120);          //   524,288
    float*          pout    = (float*)(ws + 12689408);          // 4,194,304

    const int jobs = 128 * 612 + 768 * 16 + 768 * 16 + 128 * 16; // 104,960
    prep_kernel<<<(jobs + 255) / 256, 256, 0, stream>>>(Wemb, Wih_a, Wih_b, Whh_a, Whh_b, W_beta,
                                                        wembbf, wihbf, whhbf, wbetabf);
    emb_gemm<<<512, 256, 0, stream>>>(x, wembbf, pout);
    emb_reduce<<<256, 256, 0, stream>>>(pout, emb, embbf);
    gi_gemm<<<128, 256, 0, stream>>>(embbf, wihbf, Wih_a, Wih_b, t, bih_a, bih_b, bhh_a, bhh_b, Gi3);
    retain_rec<<<256, 512, 0, stream>>>(whhbf, wbetabf, Gi3, emb, bhh_a, bhh_b,
                                        w_alpha, b_alpha, b_beta, W_out, p_g, d_g);
    reduce_out<<<256, 512, 0, stream>>>(p_g, d_g, len, b_out, (float*)d_out);
}

// Round 11
// 134.583 us; speedup vs baseline: 1.3395x; 1.2225x over previous
//
#include <hip/hip_runtime.h>
#include <hip/hip_bf16.h>

#define DEVI __device__ __forceinline__

typedef __attribute__((ext_vector_type(8))) short short8;
typedef __attribute__((ext_vector_type(8))) unsigned short ushort8;
typedef __attribute__((ext_vector_type(4))) unsigned short ushort4v;
typedef __attribute__((ext_vector_type(2))) unsigned int u32x2;
typedef __attribute__((ext_vector_type(4))) float f32x4;

static constexpr int TT = 64, KIN = 4894, KINP = 4896, E = 128;
static constexpr float L2E = 1.4426950408889634f;

DEVI unsigned short f2bf(float f) {
    union { float f; unsigned u; } v; v.f = f;
    unsigned r = v.u + 0x7fffu + ((v.u >> 16) & 1u);
    return (unsigned short)(r >> 16);
}
// args pre-scaled by log2(e): exp(x) == exp2(x*L2E)
DEVI float sigm2(float x) { return __builtin_amdgcn_rcpf(1.f + __builtin_amdgcn_exp2f(-x)); }
DEVI float tanh2(float x) { return 1.f - 2.f * __builtin_amdgcn_rcpf(__builtin_amdgcn_exp2f(x + x) + 1.f); }

// async global->LDS, 16B per lane; vmcnt-only (cannot be lgkm-drained like flat loads)
DEVI void gload16(const float* g, float* l) {
    __builtin_amdgcn_global_load_lds(
        (const __attribute__((address_space(1))) void*)g,
        (__attribute__((address_space(3))) void*)l, 16, 0, 0);
}

DEVI short8 cvt8(const float* __restrict__ p, float s) {
    float2 v0 = *(const float2*)p, v1 = *(const float2*)(p + 2);
    float2 v2 = *(const float2*)(p + 4), v3 = *(const float2*)(p + 6);
    short8 r;
    r[0] = (short)f2bf(v0.x * s); r[1] = (short)f2bf(v0.y * s);
    r[2] = (short)f2bf(v1.x * s); r[3] = (short)f2bf(v1.y * s);
    r[4] = (short)f2bf(v2.x * s); r[5] = (short)f2bf(v2.y * s);
    r[6] = (short)f2bf(v3.x * s); r[7] = (short)f2bf(v3.y * s);
    return r;
}

// ---------------- prep: weight casts (Wih/Whh/Wbeta pre-scaled by log2e) ----------------
__global__ void prep_kernel(const float* __restrict__ Wemb,
                            const float* __restrict__ Wih_a, const float* __restrict__ Wih_b,
                            const float* __restrict__ Whh_a, const float* __restrict__ Whh_b,
                            const float* __restrict__ Wbeta,
                            unsigned short* __restrict__ wembbf, unsigned short* __restrict__ wihbf,
                            unsigned short* __restrict__ whhbf, unsigned short* __restrict__ wbetabf) {
    int job = blockIdx.x * blockDim.x + threadIdx.x;
    const int JWE = 128 * 612, JWIH = 768 * 16, JWHH = 768 * 16, JWB = 128 * 16;
    if (job < JWE) {
        int row = job / 612, c8 = (job % 612) * 8;
        ushort8 v;
        #pragma unroll
        for (int jj = 0; jj < 8; ++jj) { int c = c8 + jj; v[jj] = (c < KIN) ? f2bf(Wemb[(long)row * KIN + c]) : (unsigned short)0; }
        *(ushort8*)(wembbf + (long)row * KINP + c8) = v;
        return;
    }
    job -= JWE;
    if (job < JWIH) {
        int g = job / 16, c8 = (job % 16) * 8;
        const float* src = (g < 384) ? (Wih_a + (long)g * 129) : (Wih_b + (long)(g - 384) * 129);
        ushort8 v;
        #pragma unroll
        for (int jj = 0; jj < 8; ++jj) v[jj] = f2bf(src[c8 + jj] * L2E);
        *(ushort8*)(wihbf + (long)g * 128 + c8) = v;
        return;
    }
    job -= JWIH;
    if (job < JWHH) {
        int g = job / 16, c8 = (job % 16) * 8;
        const float* src = (g < 384) ? (Whh_a + (long)g * 128) : (Whh_b + (long)(g - 384) * 128);
        ushort8 v;
        #pragma unroll
        for (int jj = 0; jj < 8; ++jj) v[jj] = f2bf(src[c8 + jj] * L2E);
        *(ushort8*)(whhbf + (long)g * 128 + c8) = v;
        return;
    }
    job -= JWHH;
    if (job < JWB) {
        int e = job / 16, c8 = (job % 16) * 8;
        ushort8 v;
        #pragma unroll
        for (int jj = 0; jj < 8; ++jj) v[jj] = f2bf(Wbeta[(long)e * 128 + c8 + jj] * L2E);
        *(ushort8*)(wbetabf + (long)e * 128 + c8) = v;
    }
}

// ---------------- emb partials: K-split GEMM, 512 blocks = (m-tile 0..127) x (ksplit 0..3) ----------------
__global__ __launch_bounds__(256) void emb_gemm(const float* __restrict__ x,
                                                const unsigned short* __restrict__ wembbf,
                                                float* __restrict__ pout) {
    const int ks = blockIdx.x & 3, m0 = (blockIdx.x >> 2) * 16;
    const int w = threadIdx.x >> 6, l = threadIdx.x & 63, lr = l & 15, lo = l >> 4;
    const int n0 = (2 * w) * 16 + lr, n1 = (2 * w + 1) * 16 + lr;
    const float* xrow = x + (long)(m0 + lr) * KIN;
    const int k0 = ks * 1216;
    f32x4 acc0 = {0, 0, 0, 0}, acc1 = {0, 0, 0, 0};
    #pragma unroll 2
    for (int kt = 0; kt < 38; ++kt) {
        int k = k0 + kt * 32 + lo * 8;
        short8 a = cvt8(xrow + k, 1.f);
        short8 b0 = *(const short8*)(wembbf + (long)n0 * KINP + k);
        short8 b1 = *(const short8*)(wembbf + (long)n1 * KINP + k);
        acc0 = __builtin_amdgcn_mfma_f32_16x16x32_bf16(a, b0, acc0, 0, 0, 0);
        acc1 = __builtin_amdgcn_mfma_f32_16x16x32_bf16(a, b1, acc1, 0, 0, 0);
    }
    if (ks == 3) {
        int k = 4864 + lo * 8;
        short8 a;
        #pragma unroll
        for (int jj = 0; jj < 8; ++jj) { int c = k + jj; a[jj] = (c < KIN) ? (short)f2bf(xrow[c]) : (short)0; }
        short8 b0 = *(const short8*)(wembbf + (long)n0 * KINP + k);
        short8 b1 = *(const short8*)(wembbf + (long)n1 * KINP + k);
        acc0 = __builtin_amdgcn_mfma_f32_16x16x32_bf16(a, b0, acc0, 0, 0, 0);
        acc1 = __builtin_amdgcn_mfma_f32_16x16x32_bf16(a, b1, acc1, 0, 0, 0);
    }
    float* pbase = pout + (long)ks * 2048 * E;
    #pragma unroll
    for (int r = 0; r < 4; ++r) {
        int m = m0 + lo * 4 + r;
        pbase[(long)m * E + n0] = acc0[r];
        pbase[(long)m * E + n1] = acc1[r];
    }
}

// ---------------- emb_reduce: sum partials -> emb_swz (chain-swizzled f32) + embbf ----------------
__global__ __launch_bounds__(256) void emb_reduce(const float* __restrict__ pout,
                                                  float* __restrict__ emb_swz, unsigned short* __restrict__ embbf) {
    const long idx = (long)blockIdx.x * 256 + threadIdx.x;
    const long base = idx * 4;
    f32x4 s = *(const f32x4*)(pout + base);
    #pragma unroll
    for (int ks = 1; ks < 4; ++ks) {
        f32x4 v = *(const f32x4*)(pout + (long)ks * 2048 * E + base);
        s[0] += v[0]; s[1] += v[1]; s[2] += v[2]; s[3] += v[3];
    }
    const long tok = base >> 7;
    const int e0 = (int)(base & 127);
    const int cc = (int)((tok >> 6) & 15);
    *(f32x4*)(emb_swz + (tok << 7) + (e0 ^ ((cc & 7) << 2))) = s;
    ushort4v h;
    #pragma unroll
    for (int jj = 0; jj < 4; ++jj) h[jj] = f2bf(s[jj]);
    *(ushort4v*)(embbf + base) = h;
}

// ---------------- Gi3: [tok][gru][gate][u ^ chain-swizzle] f32 (log2e-scaled, biases folded) ----------------
__global__ __launch_bounds__(256) void gi_gemm(const unsigned short* __restrict__ embbf,
                                               const unsigned short* __restrict__ wihbf,
                                               const float* __restrict__ Wih_a, const float* __restrict__ Wih_b,
                                               const float* __restrict__ t,
                                               const float* __restrict__ bih_a, const float* __restrict__ bih_b,
                                               const float* __restrict__ bhh_a, const float* __restrict__ bhh_b,
                                               float* __restrict__ Gi3) {
    const int m0 = blockIdx.x * 16;
    const int w = threadIdx.x >> 6, l = threadIdx.x & 63, lr = l & 15, lo = l >> 4;
    f32x4 acc[12];
    #pragma unroll
    for (int nl = 0; nl < 12; ++nl) acc[nl] = (f32x4){0, 0, 0, 0};
    #pragma unroll
    for (int kt = 0; kt < 4; ++kt) {
        int k = kt * 32 + lo * 8;
        short8 a0 = *(const short8*)(embbf + (long)(m0 + lr) * E + k);
        #pragma unroll
        for (int nl = 0; nl < 12; ++nl) {
            int n = (w * 12 + nl) * 16 + lr;
            short8 bf = *(const short8*)(wihbf + (long)n * 128 + k);
            acc[nl] = __builtin_amdgcn_mfma_f32_16x16x32_bf16(a0, bf, acc[nl], 0, 0, 0);
        }
    }
    #pragma unroll
    for (int nl = 0; nl < 12; ++nl) {
        int n = (w * 12 + nl) * 16 + lr;
        int gru = (n >= 384) ? 1 : 0;
        int nn = n - gru * 384;
        int gt = nn >> 7, u = nn & 127;
        float bias = (gru ? bih_b[nn] : bih_a[nn]);
        if (gt < 2) bias += (gru ? bhh_b[nn] : bhh_a[nn]);
        float cw = (n < 384) ? Wih_a[(long)n * 129 + 128] : Wih_b[(long)(n - 384) * 129 + 128];
        #pragma unroll
        for (int r = 0; r < 4; ++r) {
            int tok = m0 + lo * 4 + r;
            int cc = (tok >> 6) & 15;
            Gi3[(((long)tok * 2 + gru) * 3 + gt) * 128 + (u ^ ((cc & 7) << 2))] =
                acc[nl][r] + (bias + t[tok] * cw) * L2E;
        }
    }
}

// ---------------- recurrence, ONE GRU per block ----------------
// 256 blocks = (i 0..63) x (q 0..1) x (g 0..1). 512 thr, 8 waves; swapped-MFMA layout:
// thread owns (chain c = lr, features u0..u0+3). Round-11: ALL in-loop global traffic goes
// through double-buffered global_load_lds staging (vmcnt-only; issued right after the
// top-of-iteration barrier, drained by the NEXT iteration's barrier -> a full compute
// section of slack). Consume path is swizzled ds_read_b128 from LDS.
__global__ __launch_bounds__(512, 1)
void retain_rec(const unsigned short* __restrict__ whhbf, const unsigned short* __restrict__ wbetabf,
                const float* __restrict__ Gi3, const float* __restrict__ emb_swz,
                const float* __restrict__ bhh_a, const float* __restrict__ bhh_b,
                const float* __restrict__ w_alpha, const float* __restrict__ b_alpha,
                const float* __restrict__ b_beta, const float* __restrict__ Wout,
                float* __restrict__ p_g, float* __restrict__ d_g) {
    const int tid = threadIdx.x;
    const int w = tid >> 6, l = tid & 63, lr = l & 15, lo = l >> 4;
    const int i = blockIdx.x >> 2, q = (blockIdx.x >> 1) & 1, g = blockIdx.x & 1;
    const int u0 = w * 16 + lo * 4; // features; chain = lr
    const int sw2 = (lr & 7) << 2;  // dword swizzle for Gst/Est
    const int cS = tid >> 5, chk = tid & 31; // staging: row (chain) / 16B chunk

    __shared__ __align__(16) float Gst[2][3][16][128];       // 48 KB: staged gate pre-acts
    __shared__ __align__(16) float Est[2][16][128];          // 16 KB: staged emb rows (beta)
    __shared__ __align__(16) unsigned short Hbf[2][16][128]; //  8 KB
    __shared__ __align__(16) unsigned short Mld[2][16][128]; //  8 KB
    __shared__ float pd_s[16][66];

    for (int idx = tid; idx < 2 * 16 * 128; idx += 512) (&Hbf[0][0][0])[idx] = 0; // H_{-1}=0

    short8 Wf[3][4];
    #pragma unroll
    for (int gt = 0; gt < 3; ++gt)
        #pragma unroll
        for (int kt = 0; kt < 4; ++kt)
            Wf[gt][kt] = *(const short8*)(whhbf + (long)(g * 384 + gt * 128 + w * 16 + lr) * 128 + kt * 32 + lo * 8);
    short8 Xf[4]; // beta: Wbeta e-rows; alpha: w_alpha broadcast into every A row
    #pragma unroll
    for (int kt = 0; kt < 4; ++kt)
        Xf[kt] = g ? *(const short8*)(wbetabf + (long)(w * 16 + lr) * 128 + kt * 32 + lo * 8)
                   : cvt8(w_alpha + kt * 32 + lo * 8, L2E);
    short8 ones;
    #pragma unroll
    for (int jj = 0; jj < 8; ++jj) ones[jj] = (short)0x3F80;

    const float* bhhG = g ? bhh_b : bhh_a;
    f32x4 bhn4 = *(const f32x4*)(bhhG + 256 + u0);
    #pragma unroll
    for (int r = 0; r < 4; ++r) bhn4[r] *= L2E;
    f32x4 bb4 = {0, 0, 0, 0}, wo4 = {0, 0, 0, 0};
    if (g) {
        bb4 = *(const f32x4*)(b_beta + u0);
        #pragma unroll
        for (int r = 0; r < 4; ++r) bb4[r] *= L2E;
        wo4 = *(const f32x4*)(Wout + u0);
    }
    const float balL = b_alpha[0] * L2E;

    float h_old[4] = {0, 0, 0, 0};

    // staging helper: fills buf b with gate planes for token jg and (beta) emb row for token je
    const long chainBase = (long)((q * 16 + cS) * 64);
    auto STAGE = [&](int b, int jg, int je) {
        const float* gb = Gi3 + ((chainBase + jg) * 2 + g) * 384 + chk * 4;
        float* lds0 = (float*)&Gst[b][0][0][0] + (w << 8);
        gload16(gb, lds0);
        gload16(gb + 128, (float*)&Gst[b][1][0][0] + (w << 8));
        gload16(gb + 256, (float*)&Gst[b][2][0][0] + (w << 8));
        if (g) gload16(emb_swz + ((chainBase + je) << 7) + chk * 4, (float*)&Est[b][0][0] + (w << 8));
    };

    STAGE(0, i, (i + 1 > 63) ? 63 : i + 1); // preload for iter 0 (emb slot unused at n=0)

    const int iend = i + 1 + g;
    for (int n = 0; n <= iend; ++n) {
        __syncthreads(); // drains lgkm (prev ds ops) + vmcnt (stage issued a full iter ago)

        // ---- issue stage for iter n+1 ----
        {
            int jg = i - n - 1; if (jg < 0) jg = 0;
            int je = i - n;     if (je < 0) je = 0;
            STAGE((n + 1) & 1, jg, je);
        }

        const int rb = n & 1, wb = rb ^ 1, bufc = n & 1;
        const bool do_gate = (n <= i);
        const bool do_post = (n >= 1) && (n <= i + 1);

        // ---- beta wave0: d for step n-2 = ones-MFMA over Mld[wb] ----
        if (g && w == 0 && n >= 2) {
            f32x4 dacc = {0, 0, 0, 0};
            #pragma unroll
            for (int kt = 0; kt < 4; ++kt) {
                int sw = (kt * 32 + lo * 8) ^ ((lr & 7) * 8);
                short8 bm = *(const short8*)(&Mld[wb][lr][sw]);
                dacc = __builtin_amdgcn_mfma_f32_16x16x32_bf16(ones, bm, dacc, 0, 0, 0);
            }
            if (lo == 0) pd_s[lr][n - 2] = dacc[0];
        }

        // ---- B-operand fragments: H_{n-1} ----
        short8 Af[4];
        if (do_gate || do_post) {
            #pragma unroll
            for (int kt = 0; kt < 4; ++kt) {
                int sw = (kt * 32 + lo * 8) ^ ((lr & 7) * 8);
                Af[kt] = *(const short8*)(&Hbf[rb][lr][sw]);
            }
        }

        // ---- MFMA: gates, 2x2 split accumulation chains ----
        f32x4 gh0 = {0, 0, 0, 0}, gh1 = {0, 0, 0, 0}, gh2 = bhn4;
        if (do_gate) {
            f32x4 a0 = {0, 0, 0, 0}, a1 = {0, 0, 0, 0}, a2 = {0, 0, 0, 0};
            #pragma unroll
            for (int kt = 0; kt < 2; ++kt) {
                gh0 = __builtin_amdgcn_mfma_f32_16x16x32_bf16(Wf[0][kt], Af[kt], gh0, 0, 0, 0);
                gh1 = __builtin_amdgcn_mfma_f32_16x16x32_bf16(Wf[1][kt], Af[kt], gh1, 0, 0, 0);
                gh2 = __builtin_amdgcn_mfma_f32_16x16x32_bf16(Wf[2][kt], Af[kt], gh2, 0, 0, 0);
                a0 = __builtin_amdgcn_mfma_f32_16x16x32_bf16(Wf[0][kt + 2], Af[kt + 2], a0, 0, 0, 0);
                a1 = __builtin_amdgcn_mfma_f32_16x16x32_bf16(Wf[1][kt + 2], Af[kt + 2], a1, 0, 0, 0);
                a2 = __builtin_amdgcn_mfma_f32_16x16x32_bf16(Wf[2][kt + 2], Af[kt + 2], a2, 0, 0, 0);
            }
            #pragma unroll
            for (int r = 0; r < 4; ++r) { gh0[r] += a0[r]; gh1[r] += a1[r]; gh2[r] += a2[r]; }
        }

        // ---- MFMA: score (alpha) / beta preact of H_{n-1} ----
        if (do_post) {
            f32x4 xacc = {0, 0, 0, 0}, xb = {0, 0, 0, 0};
            #pragma unroll
            for (int kt = 0; kt < 2; ++kt) {
                xacc = __builtin_amdgcn_mfma_f32_16x16x32_bf16(Xf[kt], Af[kt], xacc, 0, 0, 0);
                xb   = __builtin_amdgcn_mfma_f32_16x16x32_bf16(Xf[kt + 2], Af[kt + 2], xb, 0, 0, 0);
            }
            #pragma unroll
            for (int r = 0; r < 4; ++r) xacc[r] += xb[r];
            if (!g) {
                if (w == 0 && lo == 0) pd_s[lr][n - 1] = __builtin_amdgcn_exp2f(xacc[0] + balL);
            } else {
                f32x4 ev4 = *(const f32x4*)(&Est[bufc][lr][u0 ^ sw2]);
                float m0v = tanh2(xacc[0] + bb4[0]) * ev4[0] * wo4[0];
                float m1v = tanh2(xacc[1] + bb4[1]) * ev4[1] * wo4[1];
                float m2v = tanh2(xacc[2] + bb4[2]) * ev4[2] * wo4[2];
                float m3v = tanh2(xacc[3] + bb4[3]) * ev4[3] * wo4[3];
                unsigned mp0, mp1;
                asm("v_cvt_pk_bf16_f32 %0, %1, %2" : "=v"(mp0) : "v"(m0v), "v"(m1v));
                asm("v_cvt_pk_bf16_f32 %0, %1, %2" : "=v"(mp1) : "v"(m2v), "v"(m3v));
                *(u32x2*)(&Mld[rb][lr][u0 ^ ((lr & 7) * 8)]) = (u32x2){mp0, mp1};
            }
        }

        // ---- gates: H_n = GRU(H_{n-1}, x_{i-n}); inputs from staged LDS ----
        if (do_gate) {
            f32x4 gr = *(const f32x4*)(&Gst[bufc][0][lr][u0 ^ sw2]);
            f32x4 gz = *(const f32x4*)(&Gst[bufc][1][lr][u0 ^ sw2]);
            f32x4 gn = *(const f32x4*)(&Gst[bufc][2][lr][u0 ^ sw2]);
            float hn[4];
            #pragma unroll
            for (int r = 0; r < 4; ++r) {
                float rr = sigm2(gr[r] + gh0[r]);
                float zz = sigm2(gz[r] + gh1[r]);
                float nv = tanh2(gn[r] + rr * gh2[r]);
                float h = nv + zz * (h_old[r] - nv);
                h_old[r] = h;
                hn[r] = h;
            }
            unsigned p0, p1;
            asm("v_cvt_pk_bf16_f32 %0, %1, %2" : "=v"(p0) : "v"(hn[0]), "v"(hn[1]));
            asm("v_cvt_pk_bf16_f32 %0, %1, %2" : "=v"(p1) : "v"(hn[2]), "v"(hn[3]));
            *(u32x2*)(&Hbf[wb][lr][u0 ^ ((lr & 7) * 8)]) = (u32x2){p0, p1};
        }
    }

    __syncthreads();

    // ---- bulk dump p/d ----
    float* dst = g ? d_g : p_g;
    for (int idx = tid; idx < 16 * 64; idx += 512) {
        int c = idx >> 6, kk = idx & 63;
        if (kk <= i) {
            long row = (long)(q * 16 + c) * 64 + i;
            dst[row * 64 + kk] = pd_s[c][kk];
        }
    }
}

// ---------------- reduce: out[b,i] = sum_k p*d / sum_k p + b_out ----------------
__global__ __launch_bounds__(512) void reduce_out(const float* __restrict__ p_g, const float* __restrict__ d_g,
                                                  const int* __restrict__ lengths, const float* __restrict__ b_out,
                                                  float* __restrict__ out) {
    const int w = threadIdx.x >> 6, l = threadIdx.x & 63;
    const int row = blockIdx.x * 8 + w; // b*64 + i
    const int b = row >> 6, i = row & 63;
    float p = (l <= i) ? p_g[(long)row * 64 + l] : 0.f;
    float d = (l <= i) ? d_g[(long)row * 64 + l] : 0.f;
    float pd = p * d;
    #pragma unroll
    for (int off = 1; off < 64; off <<= 1) {
        p += __shfl_xor(p, off);
        pd += __shfl_xor(pd, off);
    }
    if (l == 0) {
        float val = (i < lengths[b]) ? pd / p + b_out[0] : b_out[0];
        out[row] = val;
    }
}

// ---------------- launch ----------------
extern "C" void kernel_launch(void* const* d_in, const int* in_sizes, int n_in,
                              void* d_out, int out_size, void* d_ws, size_t ws_size,
                              hipStream_t stream) {
    (void)in_sizes; (void)n_in; (void)out_size; (void)ws_size;
    const float* x       = (const float*)d_in[0];
    const float* t       = (const float*)d_in[1];
    const int*   len     = (const int*)d_in[2];
    const float* Wemb    = (const float*)d_in[3];
    const float* Wih_a   = (const float*)d_in[4];
    const float* Whh_a   = (const float*)d_in[5];
    const float* bih_a   = (const float*)d_in[6];
    const float* bhh_a   = (const float*)d_in[7];
    const float* Wih_b   = (const float*)d_in[8];
    const float* Whh_b   = (const float*)d_in[9];
    const float* bih_b   = (const float*)d_in[10];
    const float* bhh_b   = (const float*)d_in[11];
    const float* w_alpha = (const float*)d_in[12];
    const float* b_alpha = (const float*)d_in[13];
    const float* W_beta  = (const float*)d_in[14];
    const float* b_beta  = (const float*)d_in[15];
    const float* W_out   = (const float*)d_in[16];
    const float* b_out   = (const float*)d_in[17];

    char* ws = (char*)d_ws;
    float*          emb_swz = (float*)(ws + 0);                 // 1,048,576
    unsigned short* embbf   = (unsigned short*)(ws + 1048576);  //   524,288
    float*          Gi3     = (float*)(ws + 1572864);           // 6,291,456 (tok x gru x gate x u)
    unsigned short* wembbf  = (unsigned short*)(ws + 7864320);  // 1,253,376
    unsigned short* wihbf   = (unsigned short*)(ws + 9117696);  //   196,608
    unsigned short* whhbf   = (unsigned short*)(ws + 9314304);  //   196,608
    unsigned short* wbetabf = (unsigned short*)(ws + 9510912);  //    32,768
    float*          p_g     = (float*)(ws + 9543680);           //   524,288
    float*          d_g     = (float*)(ws + 10067968);          //   524,288
    float*          pout    = (float*)(ws + 10592256);          // 4,194,304

    const int jobs = 128 * 612 + 768 * 16 + 768 * 16 + 128 * 16; // 104,960
    prep_kernel<<<(jobs + 255) / 256, 256, 0, stream>>>(Wemb, Wih_a, Wih_b, Whh_a, Whh_b, W_beta,
                                                        wembbf, wihbf, whhbf, wbetabf);
    emb_gemm<<<512, 256, 0, stream>>>(x, wembbf, pout);
    emb_reduce<<<256, 256, 0, stream>>>(pout, emb_swz, embbf);
    gi_gemm<<<128, 256, 0, stream>>>(embbf, wihbf, Wih_a, Wih_b, t, bih_a, bih_b, bhh_a, bhh_b, Gi3);
    retain_rec<<<256, 512, 0, stream>>>(whhbf, wbetabf, Gi3, emb_swz, bhh_a, bhh_b,
                                        w_alpha, b_alpha, b_beta, W_out, p_g, d_g);
    reduce_out<<<256, 512, 0, stream>>>(p_g, d_g, len, b_out, (float*)d_out);
}

// Round 12
// 134.400 us; speedup vs baseline: 1.3413x; 1.0014x over previous
//
#include <hip/hip_runtime.h>
#include <hip/hip_bf16.h>

#define DEVI __device__ __forceinline__

typedef __attribute__((ext_vector_type(8))) short short8;
typedef __attribute__((ext_vector_type(8))) unsigned short ushort8;
typedef __attribute__((ext_vector_type(2))) unsigned int u32x2;
typedef __attribute__((ext_vector_type(4))) float f32x4;

static constexpr int TT = 64, KIN = 4894, KINP = 4896, E = 128;
static constexpr float L2E = 1.4426950408889634f;

DEVI unsigned short f2bf(float f) {
    union { float f; unsigned u; } v; v.f = f;
    unsigned r = v.u + 0x7fffu + ((v.u >> 16) & 1u);
    return (unsigned short)(r >> 16);
}
// args pre-scaled by log2(e): exp(x) == exp2(x*L2E)
DEVI float sigm2(float x) { return __builtin_amdgcn_rcpf(1.f + __builtin_amdgcn_exp2f(-x)); }
DEVI float tanh2(float x) { return 1.f - 2.f * __builtin_amdgcn_rcpf(__builtin_amdgcn_exp2f(x + x) + 1.f); }

// async global->LDS, 16B per lane; vmcnt-only
DEVI void gload16(const float* g, float* l) {
    __builtin_amdgcn_global_load_lds(
        (const __attribute__((address_space(1))) void*)g,
        (__attribute__((address_space(3))) void*)l, 16, 0, 0);
}

DEVI short8 cvt8(const float* __restrict__ p, float s) { // f2bf path (L2E-scaled weights)
    float2 v0 = *(const float2*)p, v1 = *(const float2*)(p + 2);
    float2 v2 = *(const float2*)(p + 4), v3 = *(const float2*)(p + 6);
    short8 r;
    r[0] = (short)f2bf(v0.x * s); r[1] = (short)f2bf(v0.y * s);
    r[2] = (short)f2bf(v1.x * s); r[3] = (short)f2bf(v1.y * s);
    r[4] = (short)f2bf(v2.x * s); r[5] = (short)f2bf(v2.y * s);
    r[6] = (short)f2bf(v3.x * s); r[7] = (short)f2bf(v3.y * s);
    return r;
}
DEVI short8 cvt8pk(const float* __restrict__ p) { // v_cvt_pk path (hot emb_gemm loop)
    float2 v0 = *(const float2*)p, v1 = *(const float2*)(p + 2);
    float2 v2 = *(const float2*)(p + 4), v3 = *(const float2*)(p + 6);
    union { unsigned u[4]; short8 s; } o;
    asm("v_cvt_pk_bf16_f32 %0, %1, %2" : "=v"(o.u[0]) : "v"(v0.x), "v"(v0.y));
    asm("v_cvt_pk_bf16_f32 %0, %1, %2" : "=v"(o.u[1]) : "v"(v1.x), "v"(v1.y));
    asm("v_cvt_pk_bf16_f32 %0, %1, %2" : "=v"(o.u[2]) : "v"(v2.x), "v"(v2.y));
    asm("v_cvt_pk_bf16_f32 %0, %1, %2" : "=v"(o.u[3]) : "v"(v3.x), "v"(v3.y));
    return o.s;
}

// ---------------- prep: weight casts (Wih/Whh/Wbeta pre-scaled by log2e) ----------------
__global__ void prep_kernel(const float* __restrict__ Wemb,
                            const float* __restrict__ Wih_a, const float* __restrict__ Wih_b,
                            const float* __restrict__ Whh_a, const float* __restrict__ Whh_b,
                            const float* __restrict__ Wbeta,
                            unsigned short* __restrict__ wembbf, unsigned short* __restrict__ wihbf,
                            unsigned short* __restrict__ whhbf, unsigned short* __restrict__ wbetabf) {
    int job = blockIdx.x * blockDim.x + threadIdx.x;
    const int JWE = 128 * 612, JWIH = 768 * 16, JWHH = 768 * 16, JWB = 128 * 16;
    if (job < JWE) {
        int row = job / 612, c8 = (job % 612) * 8;
        ushort8 v;
        #pragma unroll
        for (int jj = 0; jj < 8; ++jj) { int c = c8 + jj; v[jj] = (c < KIN) ? f2bf(Wemb[(long)row * KIN + c]) : (unsigned short)0; }
        *(ushort8*)(wembbf + (long)row * KINP + c8) = v;
        return;
    }
    job -= JWE;
    if (job < JWIH) {
        int g = job / 16, c8 = (job % 16) * 8;
        const float* src = (g < 384) ? (Wih_a + (long)g * 129) : (Wih_b + (long)(g - 384) * 129);
        ushort8 v;
        #pragma unroll
        for (int jj = 0; jj < 8; ++jj) v[jj] = f2bf(src[c8 + jj] * L2E);
        *(ushort8*)(wihbf + (long)g * 128 + c8) = v;
        return;
    }
    job -= JWIH;
    if (job < JWHH) {
        int g = job / 16, c8 = (job % 16) * 8;
        const float* src = (g < 384) ? (Whh_a + (long)g * 128) : (Whh_b + (long)(g - 384) * 128);
        ushort8 v;
        #pragma unroll
        for (int jj = 0; jj < 8; ++jj) v[jj] = f2bf(src[c8 + jj] * L2E);
        *(ushort8*)(whhbf + (long)g * 128 + c8) = v;
        return;
    }
    job -= JWHH;
    if (job < JWB) {
        int e = job / 16, c8 = (job % 16) * 8;
        ushort8 v;
        #pragma unroll
        for (int jj = 0; jj < 8; ++jj) v[jj] = f2bf(Wbeta[(long)e * 128 + c8 + jj] * L2E);
        *(ushort8*)(wbetabf + (long)e * 128 + c8) = v;
    }
}

// ---------------- emb partials: K-split GEMM, 512 blocks = (m-tile 0..127) x (ksplit 0..3) ----------------
__global__ __launch_bounds__(256) void emb_gemm(const float* __restrict__ x,
                                                const unsigned short* __restrict__ wembbf,
                                                float* __restrict__ pout) {
    const int ks = blockIdx.x & 3, m0 = (blockIdx.x >> 2) * 16;
    const int w = threadIdx.x >> 6, l = threadIdx.x & 63, lr = l & 15, lo = l >> 4;
    const int n0 = (2 * w) * 16 + lr, n1 = (2 * w + 1) * 16 + lr;
    const float* xrow = x + (long)(m0 + lr) * KIN;
    const int k0 = ks * 1216;
    f32x4 acc0 = {0, 0, 0, 0}, acc1 = {0, 0, 0, 0};
    #pragma unroll 2
    for (int kt = 0; kt < 38; ++kt) {
        int k = k0 + kt * 32 + lo * 8;
        short8 a = cvt8pk(xrow + k);
        short8 b0 = *(const short8*)(wembbf + (long)n0 * KINP + k);
        short8 b1 = *(const short8*)(wembbf + (long)n1 * KINP + k);
        acc0 = __builtin_amdgcn_mfma_f32_16x16x32_bf16(a, b0, acc0, 0, 0, 0);
        acc1 = __builtin_amdgcn_mfma_f32_16x16x32_bf16(a, b1, acc1, 0, 0, 0);
    }
    if (ks == 3) {
        int k = 4864 + lo * 8;
        short8 a;
        #pragma unroll
        for (int jj = 0; jj < 8; ++jj) { int c = k + jj; a[jj] = (c < KIN) ? (short)f2bf(xrow[c]) : (short)0; }
        short8 b0 = *(const short8*)(wembbf + (long)n0 * KINP + k);
        short8 b1 = *(const short8*)(wembbf + (long)n1 * KINP + k);
        acc0 = __builtin_amdgcn_mfma_f32_16x16x32_bf16(a, b0, acc0, 0, 0, 0);
        acc1 = __builtin_amdgcn_mfma_f32_16x16x32_bf16(a, b1, acc1, 0, 0, 0);
    }
    float* pbase = pout + (long)ks * 2048 * E;
    #pragma unroll
    for (int r = 0; r < 4; ++r) {
        int m = m0 + lo * 4 + r;
        pbase[(long)m * E + n0] = acc0[r];
        pbase[(long)m * E + n1] = acc1[r];
    }
}

// ---------------- gi_gemm (fused emb_reduce): pout -> emb tile (LDS bf16 + global swz*Wout) -> Gi3 ----------------
__global__ __launch_bounds__(256) void gi_gemm(const float* __restrict__ pout,
                                               const unsigned short* __restrict__ wihbf,
                                               const float* __restrict__ Wih_a, const float* __restrict__ Wih_b,
                                               const float* __restrict__ t,
                                               const float* __restrict__ bih_a, const float* __restrict__ bih_b,
                                               const float* __restrict__ bhh_a, const float* __restrict__ bhh_b,
                                               const float* __restrict__ Wout,
                                               float* __restrict__ emb_swz_wo, float* __restrict__ Gi3) {
    const int m0 = blockIdx.x * 16;
    const int tid = threadIdx.x;
    const int w = tid >> 6, l = tid & 63, lr = l & 15, lo = l >> 4;
    __shared__ __align__(16) unsigned short embs[16][128];

    // ---- reduce 4 K-split partials for this block's 16 tokens ----
    {
        const int trow = tid >> 4, e0 = (tid & 15) * 8;
        const int tok = m0 + trow;
        const long base = (long)tok * E + e0;
        f32x4 s0 = *(const f32x4*)(pout + base);
        f32x4 s1 = *(const f32x4*)(pout + base + 4);
        #pragma unroll
        for (int ks = 1; ks < 4; ++ks) {
            f32x4 v0 = *(const f32x4*)(pout + (long)ks * 2048 * E + base);
            f32x4 v1 = *(const f32x4*)(pout + (long)ks * 2048 * E + base + 4);
            #pragma unroll
            for (int jj = 0; jj < 4; ++jj) { s0[jj] += v0[jj]; s1[jj] += v1[jj]; }
        }
        // bf16 tile for the MFMA below
        ushort8 h;
        #pragma unroll
        for (int jj = 0; jj < 4; ++jj) { h[jj] = f2bf(s0[jj]); h[4 + jj] = f2bf(s1[jj]); }
        *(ushort8*)(&embs[trow][e0]) = h;
        // global: emb * Wout, chain-swizzled (consumed by retain beta staging)
        f32x4 wo0 = *(const f32x4*)(Wout + e0);
        f32x4 wo1 = *(const f32x4*)(Wout + e0 + 4);
        #pragma unroll
        for (int jj = 0; jj < 4; ++jj) { s0[jj] *= wo0[jj]; s1[jj] *= wo1[jj]; }
        const int cc = (tok >> 6) & 15;
        const int x0 = e0 ^ ((cc & 7) << 2), x1 = (e0 + 4) ^ ((cc & 7) << 2);
        *(f32x4*)(emb_swz_wo + (long)tok * E + x0) = s0;
        *(f32x4*)(emb_swz_wo + (long)tok * E + x1) = s1;
    }
    __syncthreads();

    // ---- Gi GEMM: A from LDS tile, B = wihbf ----
    f32x4 acc[12];
    #pragma unroll
    for (int nl = 0; nl < 12; ++nl) acc[nl] = (f32x4){0, 0, 0, 0};
    #pragma unroll
    for (int kt = 0; kt < 4; ++kt) {
        int k = kt * 32 + lo * 8;
        short8 a0 = *(const short8*)(&embs[lr][k]);
        #pragma unroll
        for (int nl = 0; nl < 12; ++nl) {
            int n = (w * 12 + nl) * 16 + lr;
            short8 bf = *(const short8*)(wihbf + (long)n * 128 + k);
            acc[nl] = __builtin_amdgcn_mfma_f32_16x16x32_bf16(a0, bf, acc[nl], 0, 0, 0);
        }
    }
    #pragma unroll
    for (int nl = 0; nl < 12; ++nl) {
        int n = (w * 12 + nl) * 16 + lr;
        int gru = (n >= 384) ? 1 : 0;
        int nn = n - gru * 384;
        int gt = nn >> 7, u = nn & 127;
        float bias = (gru ? bih_b[nn] : bih_a[nn]);
        if (gt < 2) bias += (gru ? bhh_b[nn] : bhh_a[nn]);
        float cw = (n < 384) ? Wih_a[(long)n * 129 + 128] : Wih_b[(long)(n - 384) * 129 + 128];
        #pragma unroll
        for (int r = 0; r < 4; ++r) {
            int tok = m0 + lo * 4 + r;
            int cc = (tok >> 6) & 15;
            Gi3[(((long)tok * 2 + gru) * 3 + gt) * 128 + (u ^ ((cc & 7) << 2))] =
                acc[nl][r] + (bias + t[tok] * cw) * L2E;
        }
    }
}

// ---------------- recurrence, ONE GRU per block ----------------
// 256 blocks = (i 0..63) x (q 0..1) x (g 0..1). 512 thr, 8 waves; swapped-MFMA layout.
// Round-12: TRIPLE-buffered global_load_lds staging + counted-vmcnt barrier (T4):
// stage(n+2) issued at iter-n top; end-of-iter waits lgkmcnt(0) + vmcnt(4/3) -- drains
// stage(n+1) (issued a full 2 iterations ago), keeps stage(n+2) in flight. Staging
// latency leaves the serial critical path entirely. In-loop has NO other VMEM ops,
// so the vmcnt arithmetic is exact. sched_barrier(0) fences per methodology rule #18.
__global__ __launch_bounds__(512, 1)
void retain_rec(const unsigned short* __restrict__ whhbf, const unsigned short* __restrict__ wbetabf,
                const float* __restrict__ Gi3, const float* __restrict__ emb_swz_wo,
                const float* __restrict__ bhh_a, const float* __restrict__ bhh_b,
                const float* __restrict__ w_alpha, const float* __restrict__ b_alpha,
                const float* __restrict__ b_beta,
                float* __restrict__ p_g, float* __restrict__ d_g) {
    const int tid = threadIdx.x;
    const int w = tid >> 6, l = tid & 63, lr = l & 15, lo = l >> 4;
    const int i = blockIdx.x >> 2, q = (blockIdx.x >> 1) & 1, g = blockIdx.x & 1;
    const int u0 = w * 16 + lo * 4; // features; chain = lr
    const int sw2 = (lr & 7) << 2;  // dword swizzle for Gst/Est
    const int cS = tid >> 5, chk = tid & 31;

    __shared__ __align__(16) float Gst[3][3][16][128];       // 72 KB staged gate pre-acts
    __shared__ __align__(16) float Est[3][16][128];          // 24 KB staged emb*Wout rows
    __shared__ __align__(16) unsigned short Hbf[2][16][128]; //  8 KB
    __shared__ __align__(16) unsigned short Mld[2][16][128]; //  8 KB
    __shared__ float pd_s[16][66];

    for (int idx = tid; idx < 2 * 16 * 128; idx += 512) (&Hbf[0][0][0])[idx] = 0; // H_{-1}=0

    short8 Wf[3][4];
    #pragma unroll
    for (int gt = 0; gt < 3; ++gt)
        #pragma unroll
        for (int kt = 0; kt < 4; ++kt)
            Wf[gt][kt] = *(const short8*)(whhbf + (long)(g * 384 + gt * 128 + w * 16 + lr) * 128 + kt * 32 + lo * 8);
    short8 Xf[4]; // beta: Wbeta e-rows; alpha: w_alpha broadcast into every A row
    #pragma unroll
    for (int kt = 0; kt < 4; ++kt)
        Xf[kt] = g ? *(const short8*)(wbetabf + (long)(w * 16 + lr) * 128 + kt * 32 + lo * 8)
                   : cvt8(w_alpha + kt * 32 + lo * 8, L2E);
    short8 ones;
    #pragma unroll
    for (int jj = 0; jj < 8; ++jj) ones[jj] = (short)0x3F80;

    const float* bhhG = g ? bhh_b : bhh_a;
    f32x4 bhn4 = *(const f32x4*)(bhhG + 256 + u0);
    #pragma unroll
    for (int r = 0; r < 4; ++r) bhn4[r] *= L2E;
    f32x4 bb4 = {0, 0, 0, 0};
    if (g) {
        bb4 = *(const f32x4*)(b_beta + u0);
        #pragma unroll
        for (int r = 0; r < 4; ++r) bb4[r] *= L2E;
    }
    const float balL = b_alpha[0] * L2E;

    float h_old[4] = {0, 0, 0, 0};

    const long chainBase = (long)((q * 16 + cS) * 64);
    auto STAGE = [&](int b, int jg, int je) {
        const float* gb = Gi3 + ((chainBase + jg) * 2 + g) * 384 + chk * 4;
        gload16(gb,        (float*)&Gst[b][0][0][0] + (w << 8));
        gload16(gb + 128,  (float*)&Gst[b][1][0][0] + (w << 8));
        gload16(gb + 256,  (float*)&Gst[b][2][0][0] + (w << 8));
        if (g) gload16(emb_swz_wo + ((chainBase + je) << 7) + chk * 4, (float*)&Est[b][0][0] + (w << 8));
    };

    // preload iters 0 and 1
    STAGE(0, i, (i + 1 > 63) ? 63 : i + 1);
    STAGE(1, (i - 1 < 0) ? 0 : i - 1, i);
    if (g) asm volatile("s_waitcnt lgkmcnt(0) vmcnt(4)" ::: "memory");
    else   asm volatile("s_waitcnt lgkmcnt(0) vmcnt(3)" ::: "memory");
    __builtin_amdgcn_s_barrier();
    __builtin_amdgcn_sched_barrier(0);

    const int iend = i + 1 + g;
    for (int n = 0; n <= iend; ++n) {
        const int bufc = n % 3, bufs = (n + 2) % 3;
        const int rb = n & 1, wb = rb ^ 1;
        const bool do_gate = (n <= i);
        const bool do_post = (n >= 1) && (n <= i + 1);

        // ---- issue stage for iter n+2 (2 full iterations of slack) ----
        {
            int jg = i - n - 2; if (jg < 0) jg = 0;
            int je = i - n - 1; if (je < 0) je = 0;
            STAGE(bufs, jg, je);
        }

        // ---- beta wave0: d for step n-2 = ones-MFMA over Mld[wb] ----
        if (g && w == 0 && n >= 2) {
            f32x4 dacc = {0, 0, 0, 0};
            #pragma unroll
            for (int kt = 0; kt < 4; ++kt) {
                int sw = (kt * 32 + lo * 8) ^ ((lr & 7) * 8);
                short8 bm = *(const short8*)(&Mld[wb][lr][sw]);
                dacc = __builtin_amdgcn_mfma_f32_16x16x32_bf16(ones, bm, dacc, 0, 0, 0);
            }
            if (lo == 0) pd_s[lr][n - 2] = dacc[0];
        }

        // ---- B-operand fragments: H_{n-1} ----
        short8 Af[4];
        if (do_gate || do_post) {
            #pragma unroll
            for (int kt = 0; kt < 4; ++kt) {
                int sw = (kt * 32 + lo * 8) ^ ((lr & 7) * 8);
                Af[kt] = *(const short8*)(&Hbf[rb][lr][sw]);
            }
        }

        // ---- MFMA: gates, 2x2 split accumulation chains ----
        f32x4 gh0 = {0, 0, 0, 0}, gh1 = {0, 0, 0, 0}, gh2 = bhn4;
        if (do_gate) {
            f32x4 a0 = {0, 0, 0, 0}, a1 = {0, 0, 0, 0}, a2 = {0, 0, 0, 0};
            #pragma unroll
            for (int kt = 0; kt < 2; ++kt) {
                gh0 = __builtin_amdgcn_mfma_f32_16x16x32_bf16(Wf[0][kt], Af[kt], gh0, 0, 0, 0);
                gh1 = __builtin_amdgcn_mfma_f32_16x16x32_bf16(Wf[1][kt], Af[kt], gh1, 0, 0, 0);
                gh2 = __builtin_amdgcn_mfma_f32_16x16x32_bf16(Wf[2][kt], Af[kt], gh2, 0, 0, 0);
                a0 = __builtin_amdgcn_mfma_f32_16x16x32_bf16(Wf[0][kt + 2], Af[kt + 2], a0, 0, 0, 0);
                a1 = __builtin_amdgcn_mfma_f32_16x16x32_bf16(Wf[1][kt + 2], Af[kt + 2], a1, 0, 0, 0);
                a2 = __builtin_amdgcn_mfma_f32_16x16x32_bf16(Wf[2][kt + 2], Af[kt + 2], a2, 0, 0, 0);
            }
            #pragma unroll
            for (int r = 0; r < 4; ++r) { gh0[r] += a0[r]; gh1[r] += a1[r]; gh2[r] += a2[r]; }
        }

        // ---- MFMA: score (alpha) / beta preact of H_{n-1} ----
        if (do_post) {
            f32x4 xacc = {0, 0, 0, 0}, xb = {0, 0, 0, 0};
            #pragma unroll
            for (int kt = 0; kt < 2; ++kt) {
                xacc = __builtin_amdgcn_mfma_f32_16x16x32_bf16(Xf[kt], Af[kt], xacc, 0, 0, 0);
                xb   = __builtin_amdgcn_mfma_f32_16x16x32_bf16(Xf[kt + 2], Af[kt + 2], xb, 0, 0, 0);
            }
            #pragma unroll
            for (int r = 0; r < 4; ++r) xacc[r] += xb[r];
            if (!g) {
                if (w == 0 && lo == 0) pd_s[lr][n - 1] = __builtin_amdgcn_exp2f(xacc[0] + balL);
            } else {
                f32x4 ew4 = *(const f32x4*)(&Est[bufc][lr][u0 ^ sw2]); // emb * Wout, staged
                float m0v = tanh2(xacc[0] + bb4[0]) * ew4[0];
                float m1v = tanh2(xacc[1] + bb4[1]) * ew4[1];
                float m2v = tanh2(xacc[2] + bb4[2]) * ew4[2];
                float m3v = tanh2(xacc[3] + bb4[3]) * ew4[3];
                unsigned mp0, mp1;
                asm("v_cvt_pk_bf16_f32 %0, %1, %2" : "=v"(mp0) : "v"(m0v), "v"(m1v));
                asm("v_cvt_pk_bf16_f32 %0, %1, %2" : "=v"(mp1) : "v"(m2v), "v"(m3v));
                *(u32x2*)(&Mld[rb][lr][u0 ^ ((lr & 7) * 8)]) = (u32x2){mp0, mp1};
            }
        }

        // ---- gates: H_n = GRU(H_{n-1}, x_{i-n}); inputs from staged LDS ----
        if (do_gate) {
            f32x4 gr = *(const f32x4*)(&Gst[bufc][0][lr][u0 ^ sw2]);
            f32x4 gz = *(const f32x4*)(&Gst[bufc][1][lr][u0 ^ sw2]);
            f32x4 gn = *(const f32x4*)(&Gst[bufc][2][lr][u0 ^ sw2]);
            float hn[4];
            #pragma unroll
            for (int r = 0; r < 4; ++r) {
                float rr = sigm2(gr[r] + gh0[r]);
                float zz = sigm2(gz[r] + gh1[r]);
                float nv = tanh2(gn[r] + rr * gh2[r]);
                float h = nv + zz * (h_old[r] - nv);
                h_old[r] = h;
                hn[r] = h;
            }
            unsigned p0, p1;
            asm("v_cvt_pk_bf16_f32 %0, %1, %2" : "=v"(p0) : "v"(hn[0]), "v"(hn[1]));
            asm("v_cvt_pk_bf16_f32 %0, %1, %2" : "=v"(p1) : "v"(hn[2]), "v"(hn[3]));
            *(u32x2*)(&Hbf[wb][lr][u0 ^ ((lr & 7) * 8)]) = (u32x2){p0, p1};
        }

        // ---- counted-vmcnt barrier: drain stage(n+1), keep stage(n+2) in flight ----
        if (g) asm volatile("s_waitcnt lgkmcnt(0) vmcnt(4)" ::: "memory");
        else   asm volatile("s_waitcnt lgkmcnt(0) vmcnt(3)" ::: "memory");
        __builtin_amdgcn_s_barrier();
        __builtin_amdgcn_sched_barrier(0);
    }

    __syncthreads(); // full drain before epilogue

    // ---- bulk dump p/d ----
    float* dst = g ? d_g : p_g;
    for (int idx = tid; idx < 16 * 64; idx += 512) {
        int c = idx >> 6, kk = idx & 63;
        if (kk <= i) {
            long row = (long)(q * 16 + c) * 64 + i;
            dst[row * 64 + kk] = pd_s[c][kk];
        }
    }
}

// ---------------- reduce: out[b,i] = sum_k p*d / sum_k p + b_out ----------------
__global__ __launch_bounds__(512) void reduce_out(const float* __restrict__ p_g, const float* __restrict__ d_g,
                                                  const int* __restrict__ lengths, const float* __restrict__ b_out,
                                                  float* __restrict__ out) {
    const int w = threadIdx.x >> 6, l = threadIdx.x & 63;
    const int row = blockIdx.x * 8 + w; // b*64 + i
    const int b = row >> 6, i = row & 63;
    float p = (l <= i) ? p_g[(long)row * 64 + l] : 0.f;
    float d = (l <= i) ? d_g[(long)row * 64 + l] : 0.f;
    float pd = p * d;
    #pragma unroll
    for (int off = 1; off < 64; off <<= 1) {
        p += __shfl_xor(p, off);
        pd += __shfl_xor(pd, off);
    }
    if (l == 0) {
        float val = (i < lengths[b]) ? pd / p + b_out[0] : b_out[0];
        out[row] = val;
    }
}

// ---------------- launch ----------------
extern "C" void kernel_launch(void* const* d_in, const int* in_sizes, int n_in,
                              void* d_out, int out_size, void* d_ws, size_t ws_size,
                              hipStream_t stream) {
    (void)in_sizes; (void)n_in; (void)out_size; (void)ws_size;
    const float* x       = (const float*)d_in[0];
    const float* t       = (const float*)d_in[1];
    const int*   len     = (const int*)d_in[2];
    const float* Wemb    = (const float*)d_in[3];
    const float* Wih_a   = (const float*)d_in[4];
    const float* Whh_a   = (const float*)d_in[5];
    const float* bih_a   = (const float*)d_in[6];
    const float* bhh_a   = (const float*)d_in[7];
    const float* Wih_b   = (const float*)d_in[8];
    const float* Whh_b   = (const float*)d_in[9];
    const float* bih_b   = (const float*)d_in[10];
    const float* bhh_b   = (const float*)d_in[11];
    const float* w_alpha = (const float*)d_in[12];
    const float* b_alpha = (const float*)d_in[13];
    const float* W_beta  = (const float*)d_in[14];
    const float* b_beta  = (const float*)d_in[15];
    const float* W_out   = (const float*)d_in[16];
    const float* b_out   = (const float*)d_in[17];

    char* ws = (char*)d_ws;
    float*          emb_swz = (float*)(ws + 0);                 // 1,048,576 (emb * Wout, swizzled)
    float*          Gi3     = (float*)(ws + 1048576);           // 6,291,456 (tok x gru x gate x u^swz)
    unsigned short* wembbf  = (unsigned short*)(ws + 7340032);  // 1,253,376
    unsigned short* wihbf   = (unsigned short*)(ws + 8593408);  //   196,608
    unsigned short* whhbf   = (unsigned short*)(ws + 8790016);  //   196,608
    unsigned short* wbetabf = (unsigned short*)(ws + 8986624);  //    32,768
    float*          p_g     = (float*)(ws + 9019392);           //   524,288
    float*          d_g     = (float*)(ws + 9543680);           //   524,288
    float*          pout    = (float*)(ws + 10067968);          // 4,194,304

    const int jobs = 128 * 612 + 768 * 16 + 768 * 16 + 128 * 16; // 104,960
    prep_kernel<<<(jobs + 255) / 256, 256, 0, stream>>>(Wemb, Wih_a, Wih_b, Whh_a, Whh_b, W_beta,
                                                        wembbf, wihbf, whhbf, wbetabf);
    emb_gemm<<<512, 256, 0, stream>>>(x, wembbf, pout);
    gi_gemm<<<128, 256, 0, stream>>>(pout, wihbf, Wih_a, Wih_b, t, bih_a, bih_b, bhh_a, bhh_b,
                                     W_out, emb_swz, Gi3);
    retain_rec<<<256, 512, 0, stream>>>(whhbf, wbetabf, Gi3, emb_swz, bhh_a, bhh_b,
                                        w_alpha, b_alpha, b_beta, p_g, d_g);
    reduce_out<<<256, 512, 0, stream>>>(p_g, d_g, len, b_out, (float*)d_out);
}